// Round 4
// baseline (6964.246 us; speedup 1.0000x reference)
//
#include <hip/hip_runtime.h>
#include <hip/hip_bf16.h>

#define BB 32
#define LL 64
#define EE 1024
#define HH 128
#define VV 32000

typedef unsigned short u16;
typedef __attribute__((ext_vector_type(8))) short bf16x8;
typedef __attribute__((ext_vector_type(8))) unsigned short u16x8;
typedef __attribute__((ext_vector_type(4))) float f32x4;

#define LOG2E 1.4426950408889634f
#define C2T   2.8853900817779268f   // 2*log2(e)

// output element offsets (return order: logits, c_fin, h_fin, alphas)
#define OFF_C ((size_t)BB * LL * VV)
#define OFF_H (OFF_C + (size_t)BB * HH)
#define OFF_A (OFF_H + (size_t)BB * HH)

// ws byte offsets
#define WS_ENCT 0                    // 16,777,216 B f32 encT (reused as wT after scan)
#define WS_HS   ((size_t)16777216)   // 524,288 B bf16
#define WS_XE   ((size_t)17301504)   // 1,048,576 B f32
#define WS_GX   ((size_t)18350080)   // 4,194,304 B f32
#define WS_PAY  ((size_t)22544384)   // 270,336 B f32 payload [32][8][2][132]
#define WS_FLG  ((size_t)22814720)   // 1,024 B int flags[256]
#define WS_DFL  ((size_t)22815744)   // 4 B detect flag
#define WS_NEED ((size_t)22815748)

__device__ __forceinline__ float bf2f(u16 u) {
    union { unsigned int i; float f; } v; v.i = ((unsigned int)u) << 16; return v.f;
}
__device__ __forceinline__ u16 f2bf(float f) {
    union { float f; unsigned int i; } v; v.f = f;
    unsigned int x = v.i;
    return (u16)((x + 0x7FFFu + ((x >> 16) & 1u)) >> 16);
}
__device__ __forceinline__ float ldf(const void* p, size_t i, int f32) {
    if (f32) return ((const float*)p)[i];
    return bf2f(((const u16*)p)[i]);
}
__device__ __forceinline__ void stout(void* p, size_t i, float v, int f32) {
    if (f32) ((float*)p)[i] = v;
    else ((u16*)p)[i] = f2bf(v);
}
__device__ __forceinline__ float sigm(float x) {
    return __builtin_amdgcn_rcpf(1.f + __builtin_amdgcn_exp2f(-x * LOG2E));
}
__device__ __forceinline__ float tanh_fast(float x) {
    return 1.f - 2.f * __builtin_amdgcn_rcpf(__builtin_amdgcn_exp2f(x * C2T) + 1.f);
}

// ---- dtype detection (proven round 2) ------------------------------------
__global__ void detect_kernel(const unsigned int* __restrict__ w, int* __restrict__ flag)
{
    if (threadIdx.x == 0 && blockIdx.x == 0) {
        int cnt = 0;
        for (int i = 0; i < 256; ++i) {
            float a = fabsf(bf2f((u16)(w[i] & 0xFFFFu)));
            if (a > 1e-4f && a < 0.5f) ++cnt;
        }
        *flag = (cnt > 128) ? 1 : 0;     // 1 => inputs are bf16
    }
}

// ---- reset exchange flags (every launch: 0xAA poison / stale replay) -----
__global__ void reset_kernel(int* __restrict__ flags)
{
    __hip_atomic_store(&flags[threadIdx.x], 0, __ATOMIC_RELAXED, __HIP_MEMORY_SCOPE_AGENT);
}

// ---- x_emb = w_emb[sent] : (B*L, H) f32 ----------------------------------
__global__ __launch_bounds__(256) void gather_kernel(
    const int* __restrict__ sent, const void* __restrict__ w_emb,
    float* __restrict__ xe, const int* __restrict__ flagp)
{
    int isf32 = !flagp[0];
    int i = blockIdx.x * 256 + threadIdx.x;
    int row = i >> 7, h = i & 127;
    int id = sent[row];
    xe[(size_t)row * HH + h] = ldf(w_emb, (size_t)id * HH + h, isf32);
}

// ---- gates_x: tiled, 16 rows/block ---------------------------------------
__global__ __launch_bounds__(256) void gatesx2_kernel(
    const float* __restrict__ xe, const void* __restrict__ w_lstm,
    float* __restrict__ gx, const int* __restrict__ flagp)
{
    int isf32 = !flagp[0];
    int row0 = blockIdx.x * 16;
    int tid = threadIdx.x;
    __shared__ float xr[16][128];
    for (int i = tid; i < 2048; i += 256)
        xr[i >> 7][i & 127] = xe[(size_t)(row0 + (i >> 7)) * HH + (i & 127)];
    __syncthreads();
    int c0 = tid, c1 = tid + 256;
    float a0[16], a1[16];
    #pragma unroll
    for (int r = 0; r < 16; ++r) { a0[r] = 0.f; a1[r] = 0.f; }
    for (int kk = 0; kk < 128; ++kk) {
        float w0, w1;
        if (isf32) {
            w0 = ((const float*)w_lstm)[(size_t)kk * 512 + c0];
            w1 = ((const float*)w_lstm)[(size_t)kk * 512 + c1];
        } else {
            w0 = bf2f(((const u16*)w_lstm)[(size_t)kk * 512 + c0]);
            w1 = bf2f(((const u16*)w_lstm)[(size_t)kk * 512 + c1]);
        }
        #pragma unroll
        for (int r = 0; r < 16; ++r) {
            a0[r] += xr[r][kk] * w0;
            a1[r] += xr[r][kk] * w1;
        }
    }
    #pragma unroll
    for (int r = 0; r < 16; ++r) {
        gx[(size_t)(row0 + r) * 512 + c0] = a0[r];
        gx[(size_t)(row0 + r) * 512 + c1] = a1[r];
    }
}

// ---- w_softT = transpose(w_soft) : (VV, HH) bf16 -------------------------
__global__ __launch_bounds__(1024) void transpose_wsoft(
    const void* __restrict__ w_soft, u16* __restrict__ wT, const int* __restrict__ flagp)
{
    int isf32 = !flagp[0];
    __shared__ u16 tile[32][33];
    int n0 = blockIdx.x * 32;
    int k0 = blockIdx.y * 32;
    int tx = threadIdx.x & 31, ty = threadIdx.x >> 5;
    tile[ty][tx] = f2bf(ldf(w_soft, (size_t)(k0 + ty) * VV + n0 + tx, isf32));
    __syncthreads();
    wT[(size_t)(n0 + ty) * HH + k0 + tx] = tile[tx][ty];
}

// ---- encT[b][h][e] = C2T * (enc[b][e][:] . V_e[:][h])  f32 ---------------
__global__ __launch_bounds__(256) void encproj_kernel(
    const void* __restrict__ enc_out, const void* __restrict__ V,
    float* __restrict__ encT, const int* __restrict__ flagp)
{
    int isf32 = !flagp[0];
    __shared__ float ve[HH][HH];
    int b = blockIdx.y;
    int e0 = blockIdx.x * 64;
    int tid = threadIdx.x;
    for (int i = tid; i < HH * HH; i += 256)
        ve[i >> 7][i & 127] = ldf(V, i, isf32);
    __syncthreads();
    int e = e0 + (tid & 63);
    int hb = (tid >> 6) * 32;
    size_t rowbase = ((size_t)b * EE + e) * HH;
    float acc[32];
    #pragma unroll
    for (int i = 0; i < 32; ++i) acc[i] = 0.f;
    for (int k0 = 0; k0 < HH; k0 += 16) {
        float ef[16];
        #pragma unroll
        for (int i = 0; i < 16; ++i) ef[i] = ldf(enc_out, rowbase + k0 + i, isf32);
        #pragma unroll
        for (int hh = 0; hh < 32; ++hh) {
            float a = acc[hh];
            #pragma unroll
            for (int kk = 0; kk < 16; ++kk)
                a += ef[kk] * ve[k0 + kk][hb + hh];
            acc[hh] = a;
        }
    }
    float* outp = encT + ((size_t)b * HH) * EE + e;
    #pragma unroll
    for (int hh = 0; hh < 32; ++hh)
        outp[(size_t)(hb + hh) * EE] = acc[hh] * C2T;
}

// ---- cooperative scan: 8 blocks per batch, e-slice of 128 per block ------
// w_rec (f32) in 64 VGPRs/thread, V_h (f32) in 16 VGPRs/thread, loaded once.
__global__ __launch_bounds__(1024, 4) void scan_kernel(
    const void* __restrict__ init_c, const void* __restrict__ init_h,
    const void* __restrict__ enc_out, const void* __restrict__ w_lstm,
    const void* __restrict__ V, const float* __restrict__ encTg,
    const float* __restrict__ gx, u16* __restrict__ hs_bf,
    void* __restrict__ out, float* __restrict__ pay, int* __restrict__ flags,
    const int* __restrict__ flagp)
{
    const int isf32 = !flagp[0];
    const int bid = blockIdx.x;
    const int b = bid & 31, k = bid >> 5;
    const int tid = threadIdx.x;

    __shared__ float encTl[128][128];          // 64KB f32, C2T-prescaled slice
    __shared__ float harr[128], cst[128], hnew[128], hvC[128];
    __shared__ float gp[2][512];
    __shared__ float dred[8][128];
    __shared__ float sc[128], Ul[128];
    __shared__ float exch[8][132];
    __shared__ float redw[2], redw2[2];
    __shared__ float m_s, s_s;

    // persistent register weights
    const int colA = tid & 511, halfA = tid >> 9;
    float wreg[64];
    #pragma unroll
    for (int kk = 0; kk < 64; ++kk)
        wreg[kk] = ldf(w_lstm, (size_t)(HH + halfA * 64 + kk) * 512 + colA, isf32);
    const int hC = tid & 127, jcC = tid >> 7;
    float vreg[16];
    #pragma unroll
    for (int j = 0; j < 16; ++j)
        vreg[j] = ldf(V, (size_t)(HH + jcC * 16 + j) * HH + hC, isf32);

    for (int i = tid; i < 128 * 128; i += 1024) {
        int h = i >> 7, e = i & 127;
        encTl[h][e] = encTg[(size_t)(b * 128 + h) * EE + k * 128 + e];
    }
    if (tid < 128) {
        cst[tid]  = ldf(init_c, (size_t)b * HH + tid, isf32);
        harr[tid] = ldf(init_h, (size_t)b * HH + tid, isf32);
    }
    __syncthreads();

    float* mypay = pay + (size_t)(b * 8 + k) * 2 * 132;
    int* myflag = &flags[b * 8 + k];

    for (int t = 0; t < LL; ++t) {
        // A: recurrent gates from register weights
        {
            float acc = 0.f;
            #pragma unroll
            for (int kk = 0; kk < 64; ++kk)
                acc += harr[halfA * 64 + kk] * wreg[kk];
            gp[halfA][colA] = acc;
        }
        __syncthreads();
        // B: LSTM cell (replicated; bit-identical across the 8 blocks)
        if (tid < 128) {
            const float* gxr = gx + (size_t)(b * LL + t) * 512;
            float gi = gxr[tid]       + gp[0][tid]       + gp[1][tid];
            float gf = gxr[128 + tid] + gp[0][128 + tid] + gp[1][128 + tid];
            float go = gxr[256 + tid] + gp[0][256 + tid] + gp[1][256 + tid];
            float gg = gxr[384 + tid] + gp[0][384 + tid] + gp[1][384 + tid];
            float c_new = sigm(gf) * cst[tid] + sigm(gi) * tanh_fast(gg);
            cst[tid] = c_new;
            hnew[tid] = sigm(go) * tanh_fast(c_new);
        }
        __syncthreads();
        // C: hv[h] = h_new . V_h[:,h] from register weights
        {
            float p = 0.f;
            #pragma unroll
            for (int j = 0; j < 16; ++j)
                p += hnew[jcC * 16 + j] * vreg[j];
            dred[jcC][hC] = p;
        }
        __syncthreads();
        if (tid < 128) {
            float v = 0.f;
            #pragma unroll
            for (int s = 0; s < 8; ++s) v += dred[s][tid];
            hvC[tid] = v * C2T;
        }
        __syncthreads();
        // D: partial tanh sums over own 128-e slice (LDS only)
        {
            int e = tid & 127, hc = tid >> 7;
            float sumr = 0.f;
            #pragma unroll
            for (int j = 0; j < 16; ++j) {
                int h = hc * 16 + j;
                float a = encTl[h][e] + hvC[h];
                sumr += __builtin_amdgcn_rcpf(__builtin_amdgcn_exp2f(a) + 1.f);
            }
            dred[hc][e] = sumr;
        }
        __syncthreads();
        // E: local scores + local softmax stats
        float s_e = 0.f, p_reg = 0.f, mloc = 0.f;
        if (tid < 128) {
            float sr = 0.f;
            #pragma unroll
            for (int s = 0; s < 8; ++s) sr += dred[s][tid];
            s_e = 128.f - 2.f * sr;
            float m = s_e;
            #pragma unroll
            for (int off = 32; off; off >>= 1) m = fmaxf(m, __shfl_xor(m, off));
            if ((tid & 63) == 0) redw[tid >> 6] = m;
        }
        __syncthreads();
        if (tid < 128) {
            mloc = fmaxf(redw[0], redw[1]);
            p_reg = __builtin_amdgcn_exp2f((s_e - mloc) * LOG2E);
            sc[tid] = p_reg;
            float s = p_reg;
            #pragma unroll
            for (int off = 32; off; off >>= 1) s += __shfl_xor(s, off);
            if ((tid & 63) == 0) redw2[tid >> 6] = s;
        }
        __syncthreads();
        if (tid == 0) { m_s = mloc; s_s = redw2[0] + redw2[1]; }
        // F: partial unnormalized context over own e-slice (enc from L2)
        {
            int h = tid & 127, ec = tid >> 7;
            float p = 0.f;
            if (isf32) {
                const float* eb = (const float*)enc_out +
                    ((size_t)b * EE + k * 128 + ec * 16) * HH + h;
                #pragma unroll
                for (int j = 0; j < 16; ++j)
                    p += sc[ec * 16 + j] * eb[(size_t)j * HH];
            } else {
                const u16* eb = (const u16*)enc_out +
                    ((size_t)b * EE + k * 128 + ec * 16) * HH + h;
                #pragma unroll
                for (int j = 0; j < 16; ++j)
                    p += sc[ec * 16 + j] * bf2f(eb[(size_t)j * HH]);
            }
            __syncthreads();
            dred[ec][h] = p;
        }
        __syncthreads();
        if (tid < 128) {
            float v = 0.f;
            #pragma unroll
            for (int s = 0; s < 8; ++s) v += dred[s][tid];
            Ul[tid] = v;
        }
        __syncthreads();
        // publish payload [U(128), m, S], parity t&1; release flag = t+1
        {
            float* pp = mypay + (size_t)(t & 1) * 132;
            if (tid < 130) {
                float val = (tid < 128) ? Ul[tid] : ((tid == 128) ? m_s : s_s);
                __hip_atomic_store(&pp[tid], val, __ATOMIC_RELAXED, __HIP_MEMORY_SCOPE_AGENT);
            }
            __threadfence();
            __syncthreads();
            if (tid == 0)
                __hip_atomic_store(myflag, t + 1, __ATOMIC_RELEASE, __HIP_MEMORY_SCOPE_AGENT);
        }
        // spin on the other 7 flags
        if (tid < 8 && tid != k) {
            int cnt = 0;
            while (__hip_atomic_load(&flags[b * 8 + tid], __ATOMIC_ACQUIRE,
                                     __HIP_MEMORY_SCOPE_AGENT) < t + 1) {
                __builtin_amdgcn_s_sleep(1);
                if (++cnt > (1 << 24)) break;   // fail visibly, never hang
            }
        }
        __syncthreads();
        // gather all 8 payloads (1040 entries > 1024 threads: strided loop!)
        for (int i = tid; i < 8 * 130; i += 1024) {
            int q = i / 130, idx = i - q * 130;
            const float* qp = pay + ((size_t)(b * 8 + q) * 2 + (t & 1)) * 132;
            exch[q][idx] = __hip_atomic_load(&qp[idx], __ATOMIC_RELAXED,
                                             __HIP_MEMORY_SCOPE_AGENT);
        }
        __syncthreads();
        // combine in canonical order -> bit-identical context in all replicas
        if (tid < 128) {
            float M = exch[0][128];
            #pragma unroll
            for (int q = 1; q < 8; ++q) M = fmaxf(M, exch[q][128]);
            float St = 0.f, ch = 0.f;
            #pragma unroll
            for (int q = 0; q < 8; ++q) {
                float w = __builtin_amdgcn_exp2f((exch[q][128] - M) * LOG2E);
                St += w * exch[q][129];
                ch += w * exch[q][tid];
            }
            float rS = __builtin_amdgcn_rcpf(St);
            float ctx = ch * rS;
            harr[tid] = ctx;
            float al = sc[tid] * __builtin_amdgcn_exp2f((m_s - M) * LOG2E) * rS;
            stout(out, OFF_A + (size_t)(b * LL + t) * EE + k * 128 + tid, al, isf32);
            if (k == 0) {
                hs_bf[(size_t)(b * LL + t) * HH + tid] = f2bf(ctx);
                if (t == LL - 1) {
                    stout(out, OFF_H + (size_t)b * HH + tid, ctx, isf32);
                    stout(out, OFF_C + (size_t)b * HH + tid, cst[tid], isf32);
                }
            }
        }
        __syncthreads();
    }
}

// ---- logits = hs @ w_soft : MFMA bf16 ------------------------------------
__global__ __launch_bounds__(256) void logits_gemm(
    const u16* __restrict__ hs, const u16* __restrict__ wT,
    void* __restrict__ out, const int* __restrict__ flagp)
{
    int isf32 = !flagp[0];
    int n0 = blockIdx.x * 32;
    int m0 = (blockIdx.y * 4 + (threadIdx.x >> 6)) * 32;
    int lane = threadIdx.x & 63;
    int lr = lane & 15, lh = lane >> 4;
    f32x4 acc00 = {0.f, 0.f, 0.f, 0.f}, acc01 = acc00, acc10 = acc00, acc11 = acc00;
    const u16* a0p = hs + (size_t)(m0 + lr) * HH + lh * 8;
    const u16* a1p = a0p + (size_t)16 * HH;
    const u16* b0p = wT + (size_t)(n0 + lr) * HH + lh * 8;
    const u16* b1p = b0p + (size_t)16 * HH;
    #pragma unroll
    for (int ks = 0; ks < 4; ++ks) {
        bf16x8 a0 = *(const bf16x8*)(a0p + ks * 32);
        bf16x8 a1 = *(const bf16x8*)(a1p + ks * 32);
        bf16x8 b0 = *(const bf16x8*)(b0p + ks * 32);
        bf16x8 b1 = *(const bf16x8*)(b1p + ks * 32);
        acc00 = __builtin_amdgcn_mfma_f32_16x16x32_bf16(a0, b0, acc00, 0, 0, 0);
        acc01 = __builtin_amdgcn_mfma_f32_16x16x32_bf16(a0, b1, acc01, 0, 0, 0);
        acc10 = __builtin_amdgcn_mfma_f32_16x16x32_bf16(a1, b0, acc10, 0, 0, 0);
        acc11 = __builtin_amdgcn_mfma_f32_16x16x32_bf16(a1, b1, acc11, 0, 0, 0);
    }
    size_t base0 = (size_t)(m0 + lh * 4) * VV + n0;
    size_t base1 = (size_t)(m0 + 16 + lh * 4) * VV + n0;
    #pragma unroll
    for (int r = 0; r < 4; ++r) {
        stout(out, base0 + (size_t)r * VV + lr,      acc00[r], isf32);
        stout(out, base0 + (size_t)r * VV + 16 + lr, acc01[r], isf32);
        stout(out, base1 + (size_t)r * VV + lr,      acc10[r], isf32);
        stout(out, base1 + (size_t)r * VV + 16 + lr, acc11[r], isf32);
    }
}

extern "C" void kernel_launch(void* const* d_in, const int* in_sizes, int n_in,
                              void* d_out, int out_size, void* d_ws, size_t ws_size,
                              hipStream_t stream)
{
    (void)in_sizes; (void)n_in; (void)out_size;
    if (ws_size < WS_NEED) return;

    const int* sent     = (const int*)d_in[0];
    const void* init_c  = d_in[1];
    const void* init_h  = d_in[2];
    const void* enc_out = d_in[3];
    const void* w_emb   = d_in[4];
    const void* w_lstm  = d_in[5];
    const void* w_soft  = d_in[6];
    const void* V       = d_in[7];

    char* ws = (char*)d_ws;
    float* encT  = (float*)(ws + WS_ENCT);
    u16*   wT    = (u16*)(ws + WS_ENCT);     // reused after scan
    u16*   hs    = (u16*)(ws + WS_HS);
    float* xe    = (float*)(ws + WS_XE);
    float* gx    = (float*)(ws + WS_GX);
    float* pay   = (float*)(ws + WS_PAY);
    int*   flags = (int*)(ws + WS_FLG);
    int*   dflag = (int*)(ws + WS_DFL);

    hipLaunchKernelGGL(detect_kernel, dim3(1), dim3(64), 0, stream,
                       (const unsigned int*)w_emb, dflag);
    hipLaunchKernelGGL(reset_kernel, dim3(1), dim3(256), 0, stream, flags);
    hipLaunchKernelGGL(gather_kernel, dim3(1024), dim3(256), 0, stream, sent, w_emb, xe, dflag);
    hipLaunchKernelGGL(gatesx2_kernel, dim3(128), dim3(256), 0, stream, xe, w_lstm, gx, dflag);
    hipLaunchKernelGGL(encproj_kernel, dim3(16, BB), dim3(256), 0, stream, enc_out, V, encT, dflag);

    {
        const void* a0 = init_c; const void* a1 = init_h; const void* a2 = enc_out;
        const void* a3 = w_lstm; const void* a4 = V; const float* a5 = encT;
        const float* a6 = gx; u16* a7 = hs; void* a8 = d_out;
        float* a9 = pay; int* a10 = flags; const int* a11 = dflag;
        void* args[] = {&a0, &a1, &a2, &a3, &a4, &a5, &a6, &a7, &a8, &a9, &a10, &a11};
        hipLaunchCooperativeKernel(scan_kernel, dim3(256), dim3(1024), args, 0, stream);
    }

    hipLaunchKernelGGL(transpose_wsoft, dim3(VV / 32, 4), dim3(1024), 0, stream, w_soft, wT, dflag);
    hipLaunchKernelGGL(logits_gemm, dim3(VV / 32, 16), dim3(256), 0, stream, hs, wT, d_out, dflag);
}

// Round 5
// 892.029 us; speedup vs baseline: 7.8072x; 7.8072x over previous
//
#include <hip/hip_runtime.h>
#include <hip/hip_bf16.h>

#define BB 32
#define LL 64
#define EE 1024
#define HH 128
#define VV 32000

typedef unsigned short u16;
typedef unsigned long long u64;
typedef __attribute__((ext_vector_type(8))) short bf16x8;
typedef __attribute__((ext_vector_type(8))) unsigned short u16x8;
typedef __attribute__((ext_vector_type(4))) float f32x4;

#define LOG2E 1.4426950408889634f
#define C2T   2.8853900817779268f   // 2*log2(e)

// output element offsets (return order: logits, c_fin, h_fin, alphas)
#define OFF_C ((size_t)BB * LL * VV)
#define OFF_H (OFF_C + (size_t)BB * HH)
#define OFF_A (OFF_H + (size_t)BB * HH)

// ws byte offsets
#define WS_ENCT 0                    // 16,777,216 B f32 encT (reused as wT after scan)
#define WS_HS   ((size_t)16777216)   // 524,288 B bf16
#define WS_XE   ((size_t)17301504)   // 1,048,576 B f32
#define WS_GX   ((size_t)18350080)   // 4,194,304 B f32
#define WS_PAY  ((size_t)22544384)   // 532,480 B u64 payload [32][8][2][130]
#define WS_DFL  ((size_t)23076864)   // 4 B detect flag
#define WS_NEED ((size_t)23076868)

#define PAY_WORDS (32 * 8 * 2 * 130)   // 66,560

__device__ __forceinline__ float bf2f(u16 u) {
    union { unsigned int i; float f; } v; v.i = ((unsigned int)u) << 16; return v.f;
}
__device__ __forceinline__ u16 f2bf(float f) {
    union { float f; unsigned int i; } v; v.f = f;
    unsigned int x = v.i;
    return (u16)((x + 0x7FFFu + ((x >> 16) & 1u)) >> 16);
}
__device__ __forceinline__ float ldf(const void* p, size_t i, int f32) {
    if (f32) return ((const float*)p)[i];
    return bf2f(((const u16*)p)[i]);
}
__device__ __forceinline__ void stout(void* p, size_t i, float v, int f32) {
    if (f32) ((float*)p)[i] = v;
    else ((u16*)p)[i] = f2bf(v);
}
__device__ __forceinline__ float sigm(float x) {
    return __builtin_amdgcn_rcpf(1.f + __builtin_amdgcn_exp2f(-x * LOG2E));
}
__device__ __forceinline__ float tanh_fast(float x) {
    return 1.f - 2.f * __builtin_amdgcn_rcpf(__builtin_amdgcn_exp2f(x * C2T) + 1.f);
}

// ---- dtype detection (proven round 2) ------------------------------------
__global__ void detect_kernel(const unsigned int* __restrict__ w, int* __restrict__ flag)
{
    if (threadIdx.x == 0 && blockIdx.x == 0) {
        int cnt = 0;
        for (int i = 0; i < 256; ++i) {
            float a = fabsf(bf2f((u16)(w[i] & 0xFFFFu)));
            if (a > 1e-4f && a < 0.5f) ++cnt;
        }
        *flag = (cnt > 128) ? 1 : 0;     // 1 => inputs are bf16
    }
}

// ---- zero all payload tag words every launch (replay safety) -------------
__global__ __launch_bounds__(256) void reset_kernel(u64* __restrict__ pay)
{
    int i = blockIdx.x * 256 + threadIdx.x;
    if (i < PAY_WORDS)
        pay[i] = 0ull;
}

// ---- x_emb = w_emb[sent] : (B*L, H) f32 ----------------------------------
__global__ __launch_bounds__(256) void gather_kernel(
    const int* __restrict__ sent, const void* __restrict__ w_emb,
    float* __restrict__ xe, const int* __restrict__ flagp)
{
    int isf32 = !flagp[0];
    int i = blockIdx.x * 256 + threadIdx.x;
    int row = i >> 7, h = i & 127;
    int id = sent[row];
    xe[(size_t)row * HH + h] = ldf(w_emb, (size_t)id * HH + h, isf32);
}

// ---- gates_x: tiled, 16 rows/block ---------------------------------------
__global__ __launch_bounds__(256) void gatesx2_kernel(
    const float* __restrict__ xe, const void* __restrict__ w_lstm,
    float* __restrict__ gx, const int* __restrict__ flagp)
{
    int isf32 = !flagp[0];
    int row0 = blockIdx.x * 16;
    int tid = threadIdx.x;
    __shared__ float xr[16][128];
    for (int i = tid; i < 2048; i += 256)
        xr[i >> 7][i & 127] = xe[(size_t)(row0 + (i >> 7)) * HH + (i & 127)];
    __syncthreads();
    int c0 = tid, c1 = tid + 256;
    float a0[16], a1[16];
    #pragma unroll
    for (int r = 0; r < 16; ++r) { a0[r] = 0.f; a1[r] = 0.f; }
    for (int kk = 0; kk < 128; ++kk) {
        float w0, w1;
        if (isf32) {
            w0 = ((const float*)w_lstm)[(size_t)kk * 512 + c0];
            w1 = ((const float*)w_lstm)[(size_t)kk * 512 + c1];
        } else {
            w0 = bf2f(((const u16*)w_lstm)[(size_t)kk * 512 + c0]);
            w1 = bf2f(((const u16*)w_lstm)[(size_t)kk * 512 + c1]);
        }
        #pragma unroll
        for (int r = 0; r < 16; ++r) {
            a0[r] += xr[r][kk] * w0;
            a1[r] += xr[r][kk] * w1;
        }
    }
    #pragma unroll
    for (int r = 0; r < 16; ++r) {
        gx[(size_t)(row0 + r) * 512 + c0] = a0[r];
        gx[(size_t)(row0 + r) * 512 + c1] = a1[r];
    }
}

// ---- w_softT = transpose(w_soft) : (VV, HH) bf16 -------------------------
__global__ __launch_bounds__(1024) void transpose_wsoft(
    const void* __restrict__ w_soft, u16* __restrict__ wT, const int* __restrict__ flagp)
{
    int isf32 = !flagp[0];
    __shared__ u16 tile[32][33];
    int n0 = blockIdx.x * 32;
    int k0 = blockIdx.y * 32;
    int tx = threadIdx.x & 31, ty = threadIdx.x >> 5;
    tile[ty][tx] = f2bf(ldf(w_soft, (size_t)(k0 + ty) * VV + n0 + tx, isf32));
    __syncthreads();
    wT[(size_t)(n0 + ty) * HH + k0 + tx] = tile[tx][ty];
}

// ---- encT[b][h][e] = C2T * (enc[b][e][:] . V_e[:][h])  f32 ---------------
__global__ __launch_bounds__(256) void encproj_kernel(
    const void* __restrict__ enc_out, const void* __restrict__ V,
    float* __restrict__ encT, const int* __restrict__ flagp)
{
    int isf32 = !flagp[0];
    __shared__ float ve[HH][HH];
    int b = blockIdx.y;
    int e0 = blockIdx.x * 64;
    int tid = threadIdx.x;
    for (int i = tid; i < HH * HH; i += 256)
        ve[i >> 7][i & 127] = ldf(V, i, isf32);
    __syncthreads();
    int e = e0 + (tid & 63);
    int hb = (tid >> 6) * 32;
    size_t rowbase = ((size_t)b * EE + e) * HH;
    float acc[32];
    #pragma unroll
    for (int i = 0; i < 32; ++i) acc[i] = 0.f;
    for (int k0 = 0; k0 < HH; k0 += 16) {
        float ef[16];
        #pragma unroll
        for (int i = 0; i < 16; ++i) ef[i] = ldf(enc_out, rowbase + k0 + i, isf32);
        #pragma unroll
        for (int hh = 0; hh < 32; ++hh) {
            float a = acc[hh];
            #pragma unroll
            for (int kk = 0; kk < 16; ++kk)
                a += ef[kk] * ve[k0 + kk][hb + hh];
            acc[hh] = a;
        }
    }
    float* outp = encT + ((size_t)b * HH) * EE + e;
    #pragma unroll
    for (int hh = 0; hh < 32; ++hh)
        outp[(size_t)(hb + hh) * EE] = acc[hh] * C2T;
}

// ---- cooperative scan: 8 blocks per batch, e-slice of 128 per block ------
// Cross-block exchange via RELAXED agent atomics only (tag-packed u64 words):
// no acquire/release -> no buffer_inv/buffer_wbl2 -> L2 stays hot.
__global__ __launch_bounds__(1024, 4) void scan_kernel(
    const void* __restrict__ init_c, const void* __restrict__ init_h,
    const void* __restrict__ enc_out, const void* __restrict__ w_lstm,
    const void* __restrict__ V, const float* __restrict__ encTg,
    const float* __restrict__ gx, u16* __restrict__ hs_bf,
    void* __restrict__ out, u64* __restrict__ pay,
    const int* __restrict__ flagp)
{
    const int isf32 = !flagp[0];
    const int bid = blockIdx.x;
    const int b = bid & 31, k = bid >> 5;
    const int tid = threadIdx.x;

    __shared__ float encTl[128][128];          // 64KB f32, C2T-prescaled slice
    __shared__ float harr[128], cst[128], hnew[128], hvC[128];
    __shared__ float gp[2][512];
    __shared__ float dred[8][128];
    __shared__ float sc[128], Ul[128];
    __shared__ float exch[8][130];
    __shared__ float redw[2], redw2[2];
    __shared__ float m_s, s_s;

    for (int i = tid; i < 128 * 128; i += 1024) {
        int h = i >> 7, e = i & 127;
        encTl[h][e] = encTg[(size_t)(b * 128 + h) * EE + k * 128 + e];
    }
    if (tid < 128) {
        cst[tid]  = ldf(init_c, (size_t)b * HH + tid, isf32);
        harr[tid] = ldf(init_h, (size_t)b * HH + tid, isf32);
    }
    __syncthreads();

    u64* mypay = pay + (size_t)(b * 8 + k) * 2 * 130;

    for (int t = 0; t < LL; ++t) {
        // A: recurrent gates: h @ w_lstm[128:256,:] (coalesced L2-hot columns)
        {
            int col = tid & 511, half = tid >> 9;
            float acc = 0.f;
            if (isf32) {
                const float* wcol = (const float*)w_lstm + (size_t)(HH + half * 64) * 512 + col;
                #pragma unroll 4
                for (int kk = 0; kk < 64; ++kk)
                    acc += harr[half * 64 + kk] * wcol[(size_t)kk * 512];
            } else {
                const u16* wcol = (const u16*)w_lstm + (size_t)(HH + half * 64) * 512 + col;
                #pragma unroll 4
                for (int kk = 0; kk < 64; ++kk)
                    acc += harr[half * 64 + kk] * bf2f(wcol[(size_t)kk * 512]);
            }
            gp[half][col] = acc;
        }
        __syncthreads();
        // B: LSTM cell (replicated; bit-identical across the 8 blocks)
        if (tid < 128) {
            const float* gxr = gx + (size_t)(b * LL + t) * 512;
            float gi = gxr[tid]       + gp[0][tid]       + gp[1][tid];
            float gf = gxr[128 + tid] + gp[0][128 + tid] + gp[1][128 + tid];
            float go = gxr[256 + tid] + gp[0][256 + tid] + gp[1][256 + tid];
            float gg = gxr[384 + tid] + gp[0][384 + tid] + gp[1][384 + tid];
            float c_new = sigm(gf) * cst[tid] + sigm(gi) * tanh_fast(gg);
            cst[tid] = c_new;
            hnew[tid] = sigm(go) * tanh_fast(c_new);
        }
        __syncthreads();
        // C: hv[h] = h_new . V_h[:,h] (coalesced L2-hot columns)
        {
            int h = tid & 127, jc = tid >> 7;
            float p = 0.f;
            if (isf32) {
                const float* vp = (const float*)V + (size_t)(HH + jc * 16) * HH + h;
                #pragma unroll
                for (int j = 0; j < 16; ++j)
                    p += hnew[jc * 16 + j] * vp[(size_t)j * HH];
            } else {
                const u16* vp = (const u16*)V + (size_t)(HH + jc * 16) * HH + h;
                #pragma unroll
                for (int j = 0; j < 16; ++j)
                    p += hnew[jc * 16 + j] * bf2f(vp[(size_t)j * HH]);
            }
            dred[jc][h] = p;
        }
        __syncthreads();
        if (tid < 128) {
            float v = 0.f;
            #pragma unroll
            for (int s = 0; s < 8; ++s) v += dred[s][tid];
            hvC[tid] = v * C2T;
        }
        __syncthreads();
        // D: partial tanh sums over own 128-e slice (LDS only)
        {
            int e = tid & 127, hc = tid >> 7;
            float sumr = 0.f;
            #pragma unroll
            for (int j = 0; j < 16; ++j) {
                int h = hc * 16 + j;
                float a = encTl[h][e] + hvC[h];
                sumr += __builtin_amdgcn_rcpf(__builtin_amdgcn_exp2f(a) + 1.f);
            }
            dred[hc][e] = sumr;
        }
        __syncthreads();
        // E: local scores + local softmax stats
        float s_e = 0.f, p_reg = 0.f;
        if (tid < 128) {
            float sr = 0.f;
            #pragma unroll
            for (int s = 0; s < 8; ++s) sr += dred[s][tid];
            s_e = 128.f - 2.f * sr;
            float m = s_e;
            #pragma unroll
            for (int off = 32; off; off >>= 1) m = fmaxf(m, __shfl_xor(m, off));
            if ((tid & 63) == 0) redw[tid >> 6] = m;
        }
        __syncthreads();
        if (tid < 128) {
            float mloc = fmaxf(redw[0], redw[1]);
            p_reg = __builtin_amdgcn_exp2f((s_e - mloc) * LOG2E);
            sc[tid] = p_reg;
            float s = p_reg;
            #pragma unroll
            for (int off = 32; off; off >>= 1) s += __shfl_xor(s, off);
            if ((tid & 63) == 0) redw2[tid >> 6] = s;
            if (tid == 0) m_s = mloc;
        }
        __syncthreads();
        if (tid == 0) s_s = redw2[0] + redw2[1];
        // F: partial unnormalized context over own e-slice (L2-hot)
        {
            int h = tid & 127, ec = tid >> 7;
            float p = 0.f;
            if (isf32) {
                const float* eb = (const float*)enc_out +
                    ((size_t)b * EE + k * 128 + ec * 16) * HH + h;
                #pragma unroll
                for (int j = 0; j < 16; ++j)
                    p += sc[ec * 16 + j] * eb[(size_t)j * HH];
            } else {
                const u16* eb = (const u16*)enc_out +
                    ((size_t)b * EE + k * 128 + ec * 16) * HH + h;
                #pragma unroll
                for (int j = 0; j < 16; ++j)
                    p += sc[ec * 16 + j] * bf2f(eb[(size_t)j * HH]);
            }
            __syncthreads();
            dred[ec][h] = p;
        }
        __syncthreads();
        if (tid < 128) {
            float v = 0.f;
            #pragma unroll
            for (int s = 0; s < 8; ++s) v += dred[s][tid];
            Ul[tid] = v;
        }
        __syncthreads();
        // publish: 130 tag-packed u64 relaxed atomic stores (no fences)
        {
            u64* pp = mypay + (size_t)(t & 1) * 130;
            if (tid < 130) {
                float val = (tid < 128) ? Ul[tid] : ((tid == 128) ? m_s : s_s);
                union { float f; unsigned int u; } cv; cv.f = val;
                u64 w = ((u64)(unsigned int)(t + 1) << 32) | (u64)cv.u;
                __hip_atomic_store(&pp[tid], w, __ATOMIC_RELAXED, __HIP_MEMORY_SCOPE_AGENT);
            }
        }
        // poll 7 partners' 130 words each (910 <= 1024 threads: one word each)
        if (tid < 910) {
            int qq = tid / 130;
            int q = qq + (qq >= k ? 1 : 0);
            int idx = tid - qq * 130;
            const u64* qp = pay + ((size_t)(b * 8 + q) * 2 + (t & 1)) * 130 + idx;
            unsigned int want = (unsigned int)(t + 1);
            u64 w = __hip_atomic_load(qp, __ATOMIC_RELAXED, __HIP_MEMORY_SCOPE_AGENT);
            int cnt = 0;
            while ((unsigned int)(w >> 32) != want) {
                __builtin_amdgcn_s_sleep(2);
                w = __hip_atomic_load(qp, __ATOMIC_RELAXED, __HIP_MEMORY_SCOPE_AGENT);
                if (++cnt > (1 << 20)) break;   // fail visibly, never hang
            }
            union { unsigned int u; float f; } cv; cv.u = (unsigned int)(w & 0xFFFFFFFFu);
            exch[q][idx] = cv.f;
        }
        // own payload from LDS
        if (tid < 130) {
            float val = (tid < 128) ? Ul[tid] : ((tid == 128) ? m_s : s_s);
            exch[k][tid] = val;
        }
        __syncthreads();
        // combine in canonical order -> bit-identical context in all replicas
        if (tid < 128) {
            float M = exch[0][128];
            #pragma unroll
            for (int q = 1; q < 8; ++q) M = fmaxf(M, exch[q][128]);
            float St = 0.f, ch = 0.f;
            #pragma unroll
            for (int q = 0; q < 8; ++q) {
                float w = __builtin_amdgcn_exp2f((exch[q][128] - M) * LOG2E);
                St += w * exch[q][129];
                ch += w * exch[q][tid];
            }
            float rS = __builtin_amdgcn_rcpf(St);
            float ctx = ch * rS;
            harr[tid] = ctx;
            float al = sc[tid] * __builtin_amdgcn_exp2f((m_s - M) * LOG2E) * rS;
            stout(out, OFF_A + (size_t)(b * LL + t) * EE + k * 128 + tid, al, isf32);
            if (k == 0) {
                hs_bf[(size_t)(b * LL + t) * HH + tid] = f2bf(ctx);
                if (t == LL - 1) {
                    stout(out, OFF_H + (size_t)b * HH + tid, ctx, isf32);
                    stout(out, OFF_C + (size_t)b * HH + tid, cst[tid], isf32);
                }
            }
        }
        __syncthreads();
    }
}

// ---- logits = hs @ w_soft : MFMA bf16 ------------------------------------
__global__ __launch_bounds__(256) void logits_gemm(
    const u16* __restrict__ hs, const u16* __restrict__ wT,
    void* __restrict__ out, const int* __restrict__ flagp)
{
    int isf32 = !flagp[0];
    int n0 = blockIdx.x * 32;
    int m0 = (blockIdx.y * 4 + (threadIdx.x >> 6)) * 32;
    int lane = threadIdx.x & 63;
    int lr = lane & 15, lh = lane >> 4;
    f32x4 acc00 = {0.f, 0.f, 0.f, 0.f}, acc01 = acc00, acc10 = acc00, acc11 = acc00;
    const u16* a0p = hs + (size_t)(m0 + lr) * HH + lh * 8;
    const u16* a1p = a0p + (size_t)16 * HH;
    const u16* b0p = wT + (size_t)(n0 + lr) * HH + lh * 8;
    const u16* b1p = b0p + (size_t)16 * HH;
    #pragma unroll
    for (int ks = 0; ks < 4; ++ks) {
        bf16x8 a0 = *(const bf16x8*)(a0p + ks * 32);
        bf16x8 a1 = *(const bf16x8*)(a1p + ks * 32);
        bf16x8 b0 = *(const bf16x8*)(b0p + ks * 32);
        bf16x8 b1 = *(const bf16x8*)(b1p + ks * 32);
        acc00 = __builtin_amdgcn_mfma_f32_16x16x32_bf16(a0, b0, acc00, 0, 0, 0);
        acc01 = __builtin_amdgcn_mfma_f32_16x16x32_bf16(a0, b1, acc01, 0, 0, 0);
        acc10 = __builtin_amdgcn_mfma_f32_16x16x32_bf16(a1, b0, acc10, 0, 0, 0);
        acc11 = __builtin_amdgcn_mfma_f32_16x16x32_bf16(a1, b1, acc11, 0, 0, 0);
    }
    size_t base0 = (size_t)(m0 + lh * 4) * VV + n0;
    size_t base1 = (size_t)(m0 + 16 + lh * 4) * VV + n0;
    #pragma unroll
    for (int r = 0; r < 4; ++r) {
        stout(out, base0 + (size_t)r * VV + lr,      acc00[r], isf32);
        stout(out, base0 + (size_t)r * VV + 16 + lr, acc01[r], isf32);
        stout(out, base1 + (size_t)r * VV + lr,      acc10[r], isf32);
        stout(out, base1 + (size_t)r * VV + 16 + lr, acc11[r], isf32);
    }
}

extern "C" void kernel_launch(void* const* d_in, const int* in_sizes, int n_in,
                              void* d_out, int out_size, void* d_ws, size_t ws_size,
                              hipStream_t stream)
{
    (void)in_sizes; (void)n_in; (void)out_size;
    if (ws_size < WS_NEED) return;

    const int* sent     = (const int*)d_in[0];
    const void* init_c  = d_in[1];
    const void* init_h  = d_in[2];
    const void* enc_out = d_in[3];
    const void* w_emb   = d_in[4];
    const void* w_lstm  = d_in[5];
    const void* w_soft  = d_in[6];
    const void* V       = d_in[7];

    char* ws = (char*)d_ws;
    float* encT  = (float*)(ws + WS_ENCT);
    u16*   wT    = (u16*)(ws + WS_ENCT);     // reused after scan
    u16*   hs    = (u16*)(ws + WS_HS);
    float* xe    = (float*)(ws + WS_XE);
    float* gx    = (float*)(ws + WS_GX);
    u64*   pay   = (u64*)(ws + WS_PAY);
    int*   dflag = (int*)(ws + WS_DFL);

    hipLaunchKernelGGL(detect_kernel, dim3(1), dim3(64), 0, stream,
                       (const unsigned int*)w_emb, dflag);
    hipLaunchKernelGGL(reset_kernel, dim3((PAY_WORDS + 255) / 256), dim3(256), 0, stream, pay);
    hipLaunchKernelGGL(gather_kernel, dim3(1024), dim3(256), 0, stream, sent, w_emb, xe, dflag);
    hipLaunchKernelGGL(gatesx2_kernel, dim3(128), dim3(256), 0, stream, xe, w_lstm, gx, dflag);
    hipLaunchKernelGGL(encproj_kernel, dim3(16, BB), dim3(256), 0, stream, enc_out, V, encT, dflag);

    {
        const void* a0 = init_c; const void* a1 = init_h; const void* a2 = enc_out;
        const void* a3 = w_lstm; const void* a4 = V; const float* a5 = encT;
        const float* a6 = gx; u16* a7 = hs; void* a8 = d_out;
        u64* a9 = pay; const int* a10 = dflag;
        void* args[] = {&a0, &a1, &a2, &a3, &a4, &a5, &a6, &a7, &a8, &a9, &a10};
        hipLaunchCooperativeKernel(scan_kernel, dim3(256), dim3(1024), args, 0, stream);
    }

    hipLaunchKernelGGL(transpose_wsoft, dim3(VV / 32, 4), dim3(1024), 0, stream, w_soft, wT, dflag);
    hipLaunchKernelGGL(logits_gemm, dim3(VV / 32, 16), dim3(256), 0, stream, hs, wT, d_out, dflag);
}